// Round 22
// baseline (1563.443 us; speedup 1.0000x reference)
//
#include <hip/hip_runtime.h>

#define B_ 8
#define T_ 32000
#define NSTEP 21
#define STRIP 336                   // 21*16; 96 strips x 8 batches = 768 blocks
#define NSTRIP 96                   // = exactly one residency round at 3 blk/CU

typedef __attribute__((ext_vector_type(8))) _Float16 half8;
typedef __attribute__((ext_vector_type(4))) float f32x4;
typedef __attribute__((ext_vector_type(4))) unsigned u32x4;
typedef __attribute__((ext_vector_type(4))) unsigned short u16x4;

#define MFMA(a, b, c) __builtin_amdgcn_mfma_f32_16x16x32_f16(a, b, c, 0, 0, 0)

__device__ __forceinline__ float ftanh(float x) {
    return 1.0f - 2.0f / (1.0f + __expf(2.0f * x));
}
__device__ __forceinline__ unsigned short f2h(float x) {
    _Float16 h = (_Float16)x;
    return __builtin_bit_cast(unsigned short, h);
}
__device__ __forceinline__ float h2f(unsigned short u) {
    return (float)__builtin_bit_cast(_Float16, u);
}
// tanh(x)*sigmoid(y) with 2 exp + 1 rcp
__device__ __forceinline__ float gate(float x, float y) {
    float e2x = __expf(2.0f * x);
    float eny = __expf(-y);
    return (e2x - 1.0f) / ((e2x + 1.0f) * (1.0f + eny));
}

// transpose [L][OC][IC][3] -> [L][3][IC][OC]
__global__ void k_tr(const float* __restrict__ src, float* __restrict__ dst,
                     int L, int OC, int IC) {
    int n = L * OC * IC * 3;
    int idx = blockIdx.x * 256 + threadIdx.x;
    if (idx >= n) return;
    int j = idx % 3;
    int ic = (idx / 3) % IC;
    int oc = (idx / (3 * IC)) % OC;
    int l = idx / (3 * IC * OC);
    dst[((l * 3 + j) * IC + ic) * OC + oc] = src[idx];
}

// h = cconv(x, w_in) -> single fp16 plane
__global__ void k_in(const float* __restrict__ x, const float* __restrict__ w_in,
                     unsigned short* __restrict__ hH) {
    int t = blockIdx.x * 256 + threadIdx.x;
    int c = blockIdx.y, b = blockIdx.z;
    const float* xb = x + b * T_;
    float w0 = w_in[c * 3], w1 = w_in[c * 3 + 1], w2 = w_in[c * 3 + 2];
    float acc = w2 * xb[t];
    if (t >= 1) acc += w1 * xb[t - 1];
    if (t >= 2) acc += w0 * xb[t - 2];
    hH[(size_t)(b * 64 + c) * T_ + t] = f2h(acc);
}

// ---------------- fused residual layer (two-pass over a 336-col strip) --------
// pass A (2-term conv1): g = cconv_d(h_fp16, wres split-2); gated -> sG fp16
// pass B (prefetched RMW): o = cconv_1(gated, wskip); hout = hin + o[:64];
//         skip += o[64:]
// LDS 48.25 KB -> exactly 3 blocks/CU (hard limit: 4 thrashes L2, R8/R9/R19).
// Grid 768 = one full residency round. Interior blocks skip prefetch guards.
template <int ACC>
__global__ __launch_bounds__(256, 3)
void k_layer(const unsigned short* __restrict__ hinH,
             unsigned short* __restrict__ houtH,
             unsigned short* __restrict__ skip,
             const float* __restrict__ wrT,   // [3][64][128]
             const float* __restrict__ wkT,   // [3][64][128]
             int d) {
    __shared__ __align__(16) unsigned sH[3 * 512];             // fp16 [j][c16][icp32 swz]
    __shared__ __align__(16) unsigned short sG[(STRIP + 2) * 64]; // fp16 [gc][ic swz]

    const int tid = threadIdx.x;
    const int lane = tid & 63;
    const int ocg = tid >> 6;        // 0..3
    const int cc = lane & 15;
    const int kb = lane >> 4;        // 0..3
    const int bb = blockIdx.x & 7;           // XCD-aware: one batch per XCD
    const int tbase = (blockIdx.x >> 3) * STRIP;
    const unsigned short* hbH = hinH + (size_t)bb * 64 * T_;
    // guard-free prefetch path valid when no tap can go below 0 or past T_
    const bool interior = (tbase >= 16 + 2 * d) && (tbase + STRIP <= T_);

    half8 whA[6], wlA[6], whB[6], wlB[6];

    // ---- conv1 weights (fp16 split-2): g-channels cA (tanh), cA+64 (sig) ----
    {
        const int cA = 16 * ocg + cc, cB = cA + 64;
#pragma unroll
        for (int q = 0; q < 6; ++q) {
            const int j = q >> 1, icb = (q & 1) * 32 + kb * 8;
            const float* wp = wrT + (j * 64 + icb) * 128;
#pragma unroll
            for (int jj = 0; jj < 8; ++jj) {
                float wa = wp[jj * 128 + cA];
                _Float16 wh = (_Float16)wa;
                whA[q][jj] = wh;
                wlA[q][jj] = (_Float16)(wa - (float)wh);
                float wb = wp[jj * 128 + cB];
                wh = (_Float16)wb;
                whB[q][jj] = wh;
                wlB[q][jj] = (_Float16)(wb - (float)wh);
            }
        }
    }

    // ---- per-thread staging addresses (constant over steps) ----
    int tof[6];
    unsigned ro[6];
    int wA[6];
#pragma unroll
    for (int it = 0; it < 6; ++it) {
        int idx = it * 256 + tid;          // < 1536
        int j = idx >> 9;
        int r = idx & 511;
        int icp = r >> 4;                  // channel pair 0..31
        int c = r & 15;
        tof[it] = tbase - 16 + c - d * (2 - j);   // t at sp=0 (halo step)
        ro[it] = (unsigned)(2 * icp) * T_;
        wA[it] = j * 512 + c * 32 + (icp ^ ((c & 7) * 4));
    }

    unsigned ra[6], rb[6];
#pragma unroll
    for (int it = 0; it < 6; ++it) {
        int t = tof[it];
        ra[it] = 0u; rb[it] = 0u;
        if (t >= 0 && t < T_) { ra[it] = hbH[ro[it] + t]; rb[it] = hbH[ro[it] + T_ + t]; }
    }

    const int usb = cc * 64;               // ds_read col base (u16 units)
    const int swz = (cc & 7) * 8;
    const int cA = 16 * ocg + cc;

    // ---- pass A: NSTEP+1 steps (sp=0 is the halo step s=-1), T14 prefetch ----
    for (int sp = 0; sp < NSTEP + 1; ++sp) {
        __syncthreads();                   // WAR on sH
#pragma unroll
        for (int it = 0; it < 6; ++it) {
            sH[wA[it]] = ra[it] | (rb[it] << 16);   // (h[2icp], h[2icp+1])
        }
        __syncthreads();                   // sH visible
        // prefetch next step's values (hidden under MFMA burst + gating)
        if (sp < NSTEP) {
            if (interior) {                // wave-uniform: no bounds checks
#pragma unroll
                for (int it = 0; it < 6; ++it) {
                    int t = tof[it] + (sp + 1) * 16;
                    ra[it] = hbH[ro[it] + t];
                    rb[it] = hbH[ro[it] + T_ + t];
                }
            } else {
#pragma unroll
                for (int it = 0; it < 6; ++it) {
                    int t = tof[it] + (sp + 1) * 16;
                    unsigned va = 0u, vb = 0u;
                    if (t >= 0 && t < T_) { va = hbH[ro[it] + t]; vb = hbH[ro[it] + T_ + t]; }
                    ra[it] = va; rb[it] = vb;
                }
            }
        }

        f32x4 accA = {0.f, 0.f, 0.f, 0.f}, accB = {0.f, 0.f, 0.f, 0.f};
#pragma unroll
        for (int q = 0; q < 6; ++q) {
            const int j = q >> 1;
            const int ic0 = (q & 1) * 32 + kb * 8;
            const int us = j * 1024 + usb + (ic0 ^ swz);
            half8 ah = *(const half8*)((const unsigned short*)sH + us);
            accA = MFMA(ah, whA[q], accA);
            accA = MFMA(ah, wlA[q], accA);
            accB = MFMA(ah, whB[q], accB);
            accB = MFMA(ah, wlB[q], accB);
        }

        // gate + write fp16 into persistent gated tile
        const int gcb = (sp - 1) * 16 + kb * 4 + 2;
#pragma unroll
        for (int r = 0; r < 4; ++r) {
            int gc = gcb + r;
            if (sp > 0 || gc >= 0) {
                float gv = gate(accA[r], accB[r]);
                sG[gc * 64 + (cA ^ ((gc & 7) * 8))] = f2h(gv);
            }
        }
    }
    __syncthreads();

    // ---- conv2 weights: waves 0,1 -> residual oc, waves 2,3 -> skip oc ----
    const int oc0 = 32 * ocg + cc;
    const int oc1 = oc0 + 16;
#pragma unroll
    for (int q = 0; q < 6; ++q) {
        const int j = q >> 1, icb = (q & 1) * 32 + kb * 8;
        const float* wp = wkT + (j * 64 + icb) * 128;
#pragma unroll
        for (int jj = 0; jj < 8; ++jj) {
            float wa = wp[jj * 128 + oc0];
            _Float16 wh = (_Float16)wa;
            whA[q][jj] = wh;
            wlA[q][jj] = (_Float16)(wa - (float)wh);
            float wb = wp[jj * 128 + oc1];
            wh = (_Float16)wb;
            whB[q][jj] = wh;
            wlB[q][jj] = (_Float16)(wb - (float)wh);
        }
    }

    // ---- pass B: MFMA burst with one-step-ahead RMW prefetch (T14) ----
    if (ocg < 2) {
        const size_t r0 = ((size_t)bb * 64 + oc0) * T_ + tbase + kb * 4;
        const size_t r1 = ((size_t)bb * 64 + oc1) * T_ + tbase + kb * 4;
        u16x4 cur0 = *(const u16x4*)(hinH + r0);
        u16x4 cur1 = *(const u16x4*)(hinH + r1);
        for (int s = 0; s < NSTEP; ++s) {
            if (tbase + s * 16 >= T_) break;   // partial last strip
            // issue next step's loads before the MFMA burst
            u16x4 nxt0 = cur0, nxt1 = cur1;
            if ((s + 1 < NSTEP) && (tbase + (s + 1) * 16 < T_)) {
                nxt0 = *(const u16x4*)(hinH + r0 + (s + 1) * 16);
                nxt1 = *(const u16x4*)(hinH + r1 + (s + 1) * 16);
            }
            f32x4 aA = {0.f, 0.f, 0.f, 0.f}, aB = {0.f, 0.f, 0.f, 0.f};
#pragma unroll
            for (int q = 0; q < 6; ++q) {
                const int ic0 = (q & 1) * 32 + kb * 8;
                const int gc = s * 16 + cc + (q >> 1);
                const int us = gc * 64 + (ic0 ^ ((gc & 7) * 8));
                half8 a = *(const half8*)(sG + us);
                aA = MFMA(a, whA[q], aA);
                aA = MFMA(a, wlA[q], aA);
                aB = MFMA(a, whB[q], aB);
                aB = MFMA(a, wlB[q], aB);
            }
            u16x4 oh;
#pragma unroll
            for (int r = 0; r < 4; ++r) oh[r] = f2h(h2f(cur0[r]) + aA[r]);
            *(u16x4*)(houtH + r0 + s * 16) = oh;
#pragma unroll
            for (int r = 0; r < 4; ++r) oh[r] = f2h(h2f(cur1[r]) + aB[r]);
            *(u16x4*)(houtH + r1 + s * 16) = oh;
            cur0 = nxt0; cur1 = nxt1;
        }
    } else {
        const size_t r0 = ((size_t)bb * 64 + (oc0 - 64)) * T_ + tbase + kb * 4;
        const size_t r1 = ((size_t)bb * 64 + (oc1 - 64)) * T_ + tbase + kb * 4;
        u16x4 cur0 = {0, 0, 0, 0}, cur1 = {0, 0, 0, 0};
        if (ACC) {
            cur0 = *(const u16x4*)(skip + r0);
            cur1 = *(const u16x4*)(skip + r1);
        }
        for (int s = 0; s < NSTEP; ++s) {
            if (tbase + s * 16 >= T_) break;   // partial last strip
            u16x4 nxt0 = cur0, nxt1 = cur1;
            if (ACC && (s + 1 < NSTEP) && (tbase + (s + 1) * 16 < T_)) {
                nxt0 = *(const u16x4*)(skip + r0 + (s + 1) * 16);
                nxt1 = *(const u16x4*)(skip + r1 + (s + 1) * 16);
            }
            f32x4 aA = {0.f, 0.f, 0.f, 0.f}, aB = {0.f, 0.f, 0.f, 0.f};
#pragma unroll
            for (int q = 0; q < 6; ++q) {
                const int ic0 = (q & 1) * 32 + kb * 8;
                const int gc = s * 16 + cc + (q >> 1);
                const int us = gc * 64 + (ic0 ^ ((gc & 7) * 8));
                half8 a = *(const half8*)(sG + us);
                aA = MFMA(a, whA[q], aA);
                aA = MFMA(a, wlA[q], aA);
                aB = MFMA(a, whB[q], aB);
                aB = MFMA(a, wlB[q], aB);
            }
            u16x4 ov;
            if (ACC) {
#pragma unroll
                for (int r = 0; r < 4; ++r) ov[r] = f2h(h2f(cur0[r]) + aA[r]);
            } else {
#pragma unroll
                for (int r = 0; r < 4; ++r) ov[r] = f2h(aA[r]);
            }
            *(u16x4*)(skip + r0 + s * 16) = ov;
            if (ACC) {
#pragma unroll
                for (int r = 0; r < 4; ++r) ov[r] = f2h(h2f(cur1[r]) + aB[r]);
            } else {
#pragma unroll
                for (int r = 0; r < 4; ++r) ov[r] = f2h(aB[r]);
            }
            *(u16x4*)(skip + r1 + s * 16) = ov;
            cur0 = nxt0; cur1 = nxt1;
        }
    }
}

// ---------------- post-net 64->64 conv (k=3,d=1), fp16 in/out -----------------
// INTANH=1: apply tanh on input read (skip buffer).
template <int INTANH>
__global__ __launch_bounds__(256)
void k_post(const unsigned short* __restrict__ in_, unsigned short* __restrict__ out,
            const float* __restrict__ wT /* [3][64][64] */) {
    __shared__ __align__(16) unsigned sHi[(18 * 64) / 2];
    __shared__ __align__(16) unsigned sLo[(18 * 64) / 2];
    const int tid = threadIdx.x;
    const int lane = tid & 63;
    const int ocg = tid >> 6;
    const int cc = lane & 15;
    const int kb = lane >> 4;
    const int bb = blockIdx.y;
    const int tbase = blockIdx.x * STRIP;
    const unsigned short* ib = in_ + (size_t)bb * 64 * T_;

    const int oc = 16 * ocg + cc;
    half8 wh[6], wl[6];
#pragma unroll
    for (int q = 0; q < 6; ++q) {
        const int j = q >> 1, icb = (q & 1) * 32 + kb * 8;
        const float* wp = wT + (j * 64 + icb) * 64;
#pragma unroll
        for (int jj = 0; jj < 8; ++jj) {
            float wv = wp[jj * 64 + oc];
            _Float16 h = (_Float16)wv;
            wh[q][jj] = h;
            wl[q][jj] = (_Float16)(wv - (float)h);
        }
    }

    for (int step = 0; step < NSTEP; ++step) {
        const int t0 = tbase + step * 16;
        if (t0 >= T_) break;               // partial last strip
#pragma unroll
        for (int it = 0; it < 3; ++it) {
            int idx = it * 256 + tid;
            if (idx < 576) {
                int ic2 = idx / 18;
                int c = idx - ic2 * 18;
                int t = t0 - 2 + c;
                float v0 = 0.f, v1 = 0.f;
                if (t >= 0 && t < T_) {
                    v0 = h2f(ib[(size_t)(2 * ic2) * T_ + t]);
                    v1 = h2f(ib[(size_t)(2 * ic2 + 1) * T_ + t]);
                    if (INTANH) { v0 = ftanh(v0); v1 = ftanh(v1); }
                }
                unsigned short h0 = f2h(v0), h1 = f2h(v1);
                unsigned short l0 = f2h(v0 - h2f(h0)), l1 = f2h(v1 - h2f(h1));
                int w = c * 32 + (ic2 ^ ((c & 7) * 4));
                sHi[w] = (unsigned)h0 | ((unsigned)h1 << 16);
                sLo[w] = (unsigned)l0 | ((unsigned)l1 << 16);
            }
        }
        __syncthreads();

        f32x4 acc = {0.f, 0.f, 0.f, 0.f};
#pragma unroll
        for (int q = 0; q < 6; ++q) {
            const int j = q >> 1;
            const int ic0 = (q & 1) * 32 + kb * 8;
            const int c = cc + j;
            const int us = c * 64 + (ic0 ^ ((c & 7) * 8));
            half8 ah = *(const half8*)((const unsigned short*)sHi + us);
            half8 al = *(const half8*)((const unsigned short*)sLo + us);
            acc = MFMA(ah, wh[q], acc);
            acc = MFMA(al, wh[q], acc);
            acc = MFMA(ah, wl[q], acc);
        }
        __syncthreads();

        const int trow = t0 + kb * 4;
        u16x4 o;
#pragma unroll
        for (int r = 0; r < 4; ++r) o[r] = f2h(ftanh(acc[r]));
        *(u16x4*)(out + ((size_t)bb * 64 + oc) * T_ + trow) = o;
    }
}

// y = tanh(cconv(in, w4)), 64 -> 1 channel (fp16 input plane)
__global__ void k_last(const unsigned short* __restrict__ in,
                       const float* __restrict__ w4, float* __restrict__ y) {
    int t = blockIdx.x * 256 + threadIdx.x;
    int b = blockIdx.y;
    const unsigned short* ib = in + (size_t)b * 64 * T_;
    float acc = 0.f;
    for (int ic = 0; ic < 64; ++ic) {
        const unsigned short* r = ib + (size_t)ic * T_;
        float s = w4[ic * 3 + 2] * h2f(r[t]);
        if (t >= 1) s += w4[ic * 3 + 1] * h2f(r[t - 1]);
        if (t >= 2) s += w4[ic * 3 + 0] * h2f(r[t - 2]);
        acc += s;
    }
    y[b * T_ + t] = ftanh(acc);
}

// VNN2
__global__ void k_vnn(const float* __restrict__ y, const float* __restrict__ vw1,
                      const float* __restrict__ vw2, float* __restrict__ out) {
    int t = blockIdx.x * 256 + threadIdx.x;
    int b = blockIdx.y;
    const float* yb = y + b * T_;
    float v[5];
#pragma unroll
    for (int j = 0; j < 5; ++j) {
        int tt = t - 4 + j;
        v[j] = (tt >= 0) ? yb[tt] : 0.f;
    }
    float lin = 0.f;
#pragma unroll
    for (int j = 0; j < 5; ++j) lin += v[j] * vw1[j];
    float xa[6];
#pragma unroll
    for (int c = 0; c < 6; ++c) {
        float s = 0.f;
#pragma unroll
        for (int j = 0; j < 5; ++j) s += v[j] * vw2[c * 5 + j];
        xa[c] = s;
    }
    out[b * T_ + t] = lin + xa[0] * xa[3] + xa[1] * xa[4] + xa[2] * xa[5];
}

extern "C" void kernel_launch(void* const* d_in, const int* in_sizes, int n_in,
                              void* d_out, int out_size, void* d_ws, size_t ws_size,
                              hipStream_t stream) {
    const float* x      = (const float*)d_in[0];
    const float* w_in   = (const float*)d_in[1];
    const float* w_res  = (const float*)d_in[2];
    const float* w_skip = (const float*)d_in[3];
    const float* w2     = (const float*)d_in[4];
    const float* w3     = (const float*)d_in[5];
    const float* w4     = (const float*)d_in[6];
    const float* vw1    = (const float*)d_in[7];
    const float* vw2    = (const float*)d_in[8];

    float* ws = (float*)d_ws;
    const size_t HSZ = (size_t)B_ * 64 * T_;     // 16,384,000 elements
    unsigned short* hA   = (unsigned short*)ws;  // fp16 plane
    unsigned short* hB   = hA + HSZ;
    unsigned short* skip = hB + HSZ;             // fp16 plane
    unsigned short* pA   = skip + HSZ;           // post-net fp16 planes
    unsigned short* pB   = pA + HSZ;
    float*    y      = (float*)(pB + HSZ);
    float*    wresT  = y + (size_t)B_ * T_;
    float*    wskipT = wresT + 10 * 3 * 64 * 128;
    float*    w2T    = wskipT + 10 * 3 * 64 * 128;
    float*    w3T    = w2T + 3 * 64 * 64;

    k_tr<<<dim3(960), 256, 0, stream>>>(w_res, wresT, 10, 128, 64);
    k_tr<<<dim3(960), 256, 0, stream>>>(w_skip, wskipT, 10, 128, 64);
    k_tr<<<dim3(48), 256, 0, stream>>>(w2, w2T, 1, 64, 64);
    k_tr<<<dim3(48), 256, 0, stream>>>(w3, w3T, 1, 64, 64);

    k_in<<<dim3(T_ / 256, 64, B_), 256, 0, stream>>>(x, w_in, hA);

    unsigned short *cur = hA, *nxt = hB;
    for (int li = 0; li < 20; ++li) {
        int i = li % 10;
        int d = 1 << i;
        const float* wr = wresT + i * 3 * 64 * 128;
        const float* wk = wskipT + i * 3 * 64 * 128;
        if (li == 0)
            k_layer<0><<<dim3(NSTRIP * B_), 256, 0, stream>>>(cur, nxt, skip, wr, wk, d);
        else
            k_layer<1><<<dim3(NSTRIP * B_), 256, 0, stream>>>(cur, nxt, skip, wr, wk, d);
        unsigned short* t = cur; cur = nxt; nxt = t;
    }

    // post-net: tanh(skip) -> conv w2 (tanh) -> conv w3 (tanh) -> w4 (tanh) -> VNN
    k_post<1><<<dim3(NSTRIP, B_), 256, 0, stream>>>(skip, pB, w2T);
    k_post<0><<<dim3(NSTRIP, B_), 256, 0, stream>>>(pB, pA, w3T);
    k_last<<<dim3(T_ / 256, B_), 256, 0, stream>>>(pA, w4, y);
    k_vnn<<<dim3(T_ / 256, B_), 256, 0, stream>>>(y, vw1, vw2, (float*)d_out);
}

// Round 23
// 1546.279 us; speedup vs baseline: 1.0111x; 1.0111x over previous
//
#include <hip/hip_runtime.h>

#define B_ 8
#define T_ 32000
#define NSTEP 21
#define STRIP 336                   // 21*16; 96 strips x 8 batches = 768 blocks
#define NSTRIP 96                   // = exactly one residency round at 3 blk/CU

typedef __attribute__((ext_vector_type(8))) _Float16 half8;
typedef __attribute__((ext_vector_type(4))) float f32x4;
typedef __attribute__((ext_vector_type(4))) unsigned u32x4;
typedef __attribute__((ext_vector_type(4))) unsigned short u16x4;

#define MFMA(a, b, c) __builtin_amdgcn_mfma_f32_16x16x32_f16(a, b, c, 0, 0, 0)

__device__ __forceinline__ float ftanh(float x) {
    return 1.0f - 2.0f / (1.0f + __expf(2.0f * x));
}
__device__ __forceinline__ unsigned short f2h(float x) {
    _Float16 h = (_Float16)x;
    return __builtin_bit_cast(unsigned short, h);
}
__device__ __forceinline__ float h2f(unsigned short u) {
    return (float)__builtin_bit_cast(_Float16, u);
}
// tanh(x)*sigmoid(y) with 2 exp + 1 rcp
__device__ __forceinline__ float gate(float x, float y) {
    float e2x = __expf(2.0f * x);
    float eny = __expf(-y);
    return (e2x - 1.0f) / ((e2x + 1.0f) * (1.0f + eny));
}

// transpose [L][OC][IC][3] -> [L][3][IC][OC]
__global__ void k_tr(const float* __restrict__ src, float* __restrict__ dst,
                     int L, int OC, int IC) {
    int n = L * OC * IC * 3;
    int idx = blockIdx.x * 256 + threadIdx.x;
    if (idx >= n) return;
    int j = idx % 3;
    int ic = (idx / 3) % IC;
    int oc = (idx / (3 * IC)) % OC;
    int l = idx / (3 * IC * OC);
    dst[((l * 3 + j) * IC + ic) * OC + oc] = src[idx];
}

// h = cconv(x, w_in) -> single fp16 plane
__global__ void k_in(const float* __restrict__ x, const float* __restrict__ w_in,
                     unsigned short* __restrict__ hH) {
    int t = blockIdx.x * 256 + threadIdx.x;
    int c = blockIdx.y, b = blockIdx.z;
    const float* xb = x + b * T_;
    float w0 = w_in[c * 3], w1 = w_in[c * 3 + 1], w2 = w_in[c * 3 + 2];
    float acc = w2 * xb[t];
    if (t >= 1) acc += w1 * xb[t - 1];
    if (t >= 2) acc += w0 * xb[t - 2];
    hH[(size_t)(b * 64 + c) * T_ + t] = f2h(acc);
}

// ---------------- fused residual layer (two-pass over a 336-col strip) --------
// pass A (2-term conv1): g = cconv_d(h_fp16, wres split-2); gated -> sG fp16
// pass B: o = cconv_1(gated, wskip); hout = hin + o[:64] (fp16); skip += o[64:]
// LDS 48.25 KB -> exactly 3 blocks/CU (hard limit: 4 thrashes L2, R8/R9/R19).
// Grid 768 = one full residency round. Interior blocks skip prefetch guards.
// NOTE: pass-B RMW prefetch tested R22 -> WRITE +20MB, net regression; keep inline loads.
template <int ACC>
__global__ __launch_bounds__(256, 3)
void k_layer(const unsigned short* __restrict__ hinH,
             unsigned short* __restrict__ houtH,
             unsigned short* __restrict__ skip,
             const float* __restrict__ wrT,   // [3][64][128]
             const float* __restrict__ wkT,   // [3][64][128]
             int d) {
    __shared__ __align__(16) unsigned sH[3 * 512];             // fp16 [j][c16][icp32 swz]
    __shared__ __align__(16) unsigned short sG[(STRIP + 2) * 64]; // fp16 [gc][ic swz]

    const int tid = threadIdx.x;
    const int lane = tid & 63;
    const int ocg = tid >> 6;        // 0..3
    const int cc = lane & 15;
    const int kb = lane >> 4;        // 0..3
    const int bb = blockIdx.x & 7;           // XCD-aware: one batch per XCD
    const int tbase = (blockIdx.x >> 3) * STRIP;
    const unsigned short* hbH = hinH + (size_t)bb * 64 * T_;
    // guard-free prefetch path valid when no tap can go below 0 or past T_
    const bool interior = (tbase >= 16 + 2 * d) && (tbase + STRIP <= T_);

    half8 whA[6], wlA[6], whB[6], wlB[6];

    // ---- conv1 weights (fp16 split-2): g-channels cA (tanh), cA+64 (sig) ----
    {
        const int cA = 16 * ocg + cc, cB = cA + 64;
#pragma unroll
        for (int q = 0; q < 6; ++q) {
            const int j = q >> 1, icb = (q & 1) * 32 + kb * 8;
            const float* wp = wrT + (j * 64 + icb) * 128;
#pragma unroll
            for (int jj = 0; jj < 8; ++jj) {
                float wa = wp[jj * 128 + cA];
                _Float16 wh = (_Float16)wa;
                whA[q][jj] = wh;
                wlA[q][jj] = (_Float16)(wa - (float)wh);
                float wb = wp[jj * 128 + cB];
                wh = (_Float16)wb;
                whB[q][jj] = wh;
                wlB[q][jj] = (_Float16)(wb - (float)wh);
            }
        }
    }

    // ---- per-thread staging addresses (constant over steps) ----
    int tof[6];
    unsigned ro[6];
    int wA[6];
#pragma unroll
    for (int it = 0; it < 6; ++it) {
        int idx = it * 256 + tid;          // < 1536
        int j = idx >> 9;
        int r = idx & 511;
        int icp = r >> 4;                  // channel pair 0..31
        int c = r & 15;
        tof[it] = tbase - 16 + c - d * (2 - j);   // t at sp=0 (halo step)
        ro[it] = (unsigned)(2 * icp) * T_;
        wA[it] = j * 512 + c * 32 + (icp ^ ((c & 7) * 4));
    }

    unsigned ra[6], rb[6];
#pragma unroll
    for (int it = 0; it < 6; ++it) {
        int t = tof[it];
        ra[it] = 0u; rb[it] = 0u;
        if (t >= 0 && t < T_) { ra[it] = hbH[ro[it] + t]; rb[it] = hbH[ro[it] + T_ + t]; }
    }

    const int usb = cc * 64;               // ds_read col base (u16 units)
    const int swz = (cc & 7) * 8;
    const int cA = 16 * ocg + cc;

    // ---- pass A: NSTEP+1 steps (sp=0 is the halo step s=-1), T14 prefetch ----
    for (int sp = 0; sp < NSTEP + 1; ++sp) {
        __syncthreads();                   // WAR on sH
#pragma unroll
        for (int it = 0; it < 6; ++it) {
            sH[wA[it]] = ra[it] | (rb[it] << 16);   // (h[2icp], h[2icp+1])
        }
        __syncthreads();                   // sH visible
        // prefetch next step's values (hidden under MFMA burst + gating)
        if (sp < NSTEP) {
            if (interior) {                // wave-uniform: no bounds checks
#pragma unroll
                for (int it = 0; it < 6; ++it) {
                    int t = tof[it] + (sp + 1) * 16;
                    ra[it] = hbH[ro[it] + t];
                    rb[it] = hbH[ro[it] + T_ + t];
                }
            } else {
#pragma unroll
                for (int it = 0; it < 6; ++it) {
                    int t = tof[it] + (sp + 1) * 16;
                    unsigned va = 0u, vb = 0u;
                    if (t >= 0 && t < T_) { va = hbH[ro[it] + t]; vb = hbH[ro[it] + T_ + t]; }
                    ra[it] = va; rb[it] = vb;
                }
            }
        }

        f32x4 accA = {0.f, 0.f, 0.f, 0.f}, accB = {0.f, 0.f, 0.f, 0.f};
#pragma unroll
        for (int q = 0; q < 6; ++q) {
            const int j = q >> 1;
            const int ic0 = (q & 1) * 32 + kb * 8;
            const int us = j * 1024 + usb + (ic0 ^ swz);
            half8 ah = *(const half8*)((const unsigned short*)sH + us);
            accA = MFMA(ah, whA[q], accA);
            accA = MFMA(ah, wlA[q], accA);
            accB = MFMA(ah, whB[q], accB);
            accB = MFMA(ah, wlB[q], accB);
        }

        // gate + write fp16 into persistent gated tile
        const int gcb = (sp - 1) * 16 + kb * 4 + 2;
#pragma unroll
        for (int r = 0; r < 4; ++r) {
            int gc = gcb + r;
            if (sp > 0 || gc >= 0) {
                float gv = gate(accA[r], accB[r]);
                sG[gc * 64 + (cA ^ ((gc & 7) * 8))] = f2h(gv);
            }
        }
    }
    __syncthreads();

    // ---- conv2 weights: waves 0,1 -> residual oc, waves 2,3 -> skip oc ----
    const int oc0 = 32 * ocg + cc;
    const int oc1 = oc0 + 16;
#pragma unroll
    for (int q = 0; q < 6; ++q) {
        const int j = q >> 1, icb = (q & 1) * 32 + kb * 8;
        const float* wp = wkT + (j * 64 + icb) * 128;
#pragma unroll
        for (int jj = 0; jj < 8; ++jj) {
            float wa = wp[jj * 128 + oc0];
            _Float16 wh = (_Float16)wa;
            whA[q][jj] = wh;
            wlA[q][jj] = (_Float16)(wa - (float)wh);
            float wb = wp[jj * 128 + oc1];
            wh = (_Float16)wb;
            whB[q][jj] = wh;
            wlB[q][jj] = (_Float16)(wb - (float)wh);
        }
    }

    // ---- pass B: pure MFMA burst (A-operand exact fp16 -> 2-term) ----
    for (int s = 0; s < NSTEP; ++s) {
        if (tbase + s * 16 >= T_) break;   // partial last strip (80-col tail)
        f32x4 aA = {0.f, 0.f, 0.f, 0.f}, aB = {0.f, 0.f, 0.f, 0.f};
#pragma unroll
        for (int q = 0; q < 6; ++q) {
            const int ic0 = (q & 1) * 32 + kb * 8;
            const int gc = s * 16 + cc + (q >> 1);
            const int us = gc * 64 + (ic0 ^ ((gc & 7) * 8));
            half8 a = *(const half8*)(sG + us);
            aA = MFMA(a, whA[q], aA);
            aA = MFMA(a, wlA[q], aA);
            aB = MFMA(a, whB[q], aB);
            aB = MFMA(a, wlB[q], aB);
        }
        const int trow = tbase + s * 16 + kb * 4;
        if (ocg < 2) {
            // residual channels: fp16 carry
            size_t o0 = ((size_t)bb * 64 + oc0) * T_ + trow;
            u16x4 hiv = *(const u16x4*)(hinH + o0);
            u16x4 oh;
#pragma unroll
            for (int r = 0; r < 4; ++r) oh[r] = f2h(h2f(hiv[r]) + aA[r]);
            *(u16x4*)(houtH + o0) = oh;
            size_t o1 = ((size_t)bb * 64 + oc1) * T_ + trow;
            hiv = *(const u16x4*)(hinH + o1);
#pragma unroll
            for (int r = 0; r < 4; ++r) oh[r] = f2h(h2f(hiv[r]) + aB[r]);
            *(u16x4*)(houtH + o1) = oh;
        } else {
            // skip channels: single fp16 plane RMW
            size_t o0 = ((size_t)bb * 64 + (oc0 - 64)) * T_ + trow;
            u16x4 ov;
            if (ACC) {
                u16x4 sv = *(const u16x4*)(skip + o0);
#pragma unroll
                for (int r = 0; r < 4; ++r) ov[r] = f2h(h2f(sv[r]) + aA[r]);
            } else {
#pragma unroll
                for (int r = 0; r < 4; ++r) ov[r] = f2h(aA[r]);
            }
            *(u16x4*)(skip + o0) = ov;
            size_t o1 = ((size_t)bb * 64 + (oc1 - 64)) * T_ + trow;
            if (ACC) {
                u16x4 sv = *(const u16x4*)(skip + o1);
#pragma unroll
                for (int r = 0; r < 4; ++r) ov[r] = f2h(h2f(sv[r]) + aB[r]);
            } else {
#pragma unroll
                for (int r = 0; r < 4; ++r) ov[r] = f2h(aB[r]);
            }
            *(u16x4*)(skip + o1) = ov;
        }
    }
}

// ---------------- post-net 64->64 conv (k=3,d=1), fp16 in/out -----------------
// INTANH=1: apply tanh on input read (skip buffer).
template <int INTANH>
__global__ __launch_bounds__(256)
void k_post(const unsigned short* __restrict__ in_, unsigned short* __restrict__ out,
            const float* __restrict__ wT /* [3][64][64] */) {
    __shared__ __align__(16) unsigned sHi[(18 * 64) / 2];
    __shared__ __align__(16) unsigned sLo[(18 * 64) / 2];
    const int tid = threadIdx.x;
    const int lane = tid & 63;
    const int ocg = tid >> 6;
    const int cc = lane & 15;
    const int kb = lane >> 4;
    const int bb = blockIdx.y;
    const int tbase = blockIdx.x * STRIP;
    const unsigned short* ib = in_ + (size_t)bb * 64 * T_;

    const int oc = 16 * ocg + cc;
    half8 wh[6], wl[6];
#pragma unroll
    for (int q = 0; q < 6; ++q) {
        const int j = q >> 1, icb = (q & 1) * 32 + kb * 8;
        const float* wp = wT + (j * 64 + icb) * 64;
#pragma unroll
        for (int jj = 0; jj < 8; ++jj) {
            float wv = wp[jj * 64 + oc];
            _Float16 h = (_Float16)wv;
            wh[q][jj] = h;
            wl[q][jj] = (_Float16)(wv - (float)h);
        }
    }

    for (int step = 0; step < NSTEP; ++step) {
        const int t0 = tbase + step * 16;
        if (t0 >= T_) break;               // partial last strip
#pragma unroll
        for (int it = 0; it < 3; ++it) {
            int idx = it * 256 + tid;
            if (idx < 576) {
                int ic2 = idx / 18;
                int c = idx - ic2 * 18;
                int t = t0 - 2 + c;
                float v0 = 0.f, v1 = 0.f;
                if (t >= 0 && t < T_) {
                    v0 = h2f(ib[(size_t)(2 * ic2) * T_ + t]);
                    v1 = h2f(ib[(size_t)(2 * ic2 + 1) * T_ + t]);
                    if (INTANH) { v0 = ftanh(v0); v1 = ftanh(v1); }
                }
                unsigned short h0 = f2h(v0), h1 = f2h(v1);
                unsigned short l0 = f2h(v0 - h2f(h0)), l1 = f2h(v1 - h2f(h1));
                int w = c * 32 + (ic2 ^ ((c & 7) * 4));
                sHi[w] = (unsigned)h0 | ((unsigned)h1 << 16);
                sLo[w] = (unsigned)l0 | ((unsigned)l1 << 16);
            }
        }
        __syncthreads();

        f32x4 acc = {0.f, 0.f, 0.f, 0.f};
#pragma unroll
        for (int q = 0; q < 6; ++q) {
            const int j = q >> 1;
            const int ic0 = (q & 1) * 32 + kb * 8;
            const int c = cc + j;
            const int us = c * 64 + (ic0 ^ ((c & 7) * 8));
            half8 ah = *(const half8*)((const unsigned short*)sHi + us);
            half8 al = *(const half8*)((const unsigned short*)sLo + us);
            acc = MFMA(ah, wh[q], acc);
            acc = MFMA(al, wh[q], acc);
            acc = MFMA(ah, wl[q], acc);
        }
        __syncthreads();

        const int trow = t0 + kb * 4;
        u16x4 o;
#pragma unroll
        for (int r = 0; r < 4; ++r) o[r] = f2h(ftanh(acc[r]));
        *(u16x4*)(out + ((size_t)bb * 64 + oc) * T_ + trow) = o;
    }
}

// y = tanh(cconv(in, w4)), 64 -> 1 channel (fp16 input plane)
__global__ void k_last(const unsigned short* __restrict__ in,
                       const float* __restrict__ w4, float* __restrict__ y) {
    int t = blockIdx.x * 256 + threadIdx.x;
    int b = blockIdx.y;
    const unsigned short* ib = in + (size_t)b * 64 * T_;
    float acc = 0.f;
    for (int ic = 0; ic < 64; ++ic) {
        const unsigned short* r = ib + (size_t)ic * T_;
        float s = w4[ic * 3 + 2] * h2f(r[t]);
        if (t >= 1) s += w4[ic * 3 + 1] * h2f(r[t - 1]);
        if (t >= 2) s += w4[ic * 3 + 0] * h2f(r[t - 2]);
        acc += s;
    }
    y[b * T_ + t] = ftanh(acc);
}

// VNN2
__global__ void k_vnn(const float* __restrict__ y, const float* __restrict__ vw1,
                      const float* __restrict__ vw2, float* __restrict__ out) {
    int t = blockIdx.x * 256 + threadIdx.x;
    int b = blockIdx.y;
    const float* yb = y + b * T_;
    float v[5];
#pragma unroll
    for (int j = 0; j < 5; ++j) {
        int tt = t - 4 + j;
        v[j] = (tt >= 0) ? yb[tt] : 0.f;
    }
    float lin = 0.f;
#pragma unroll
    for (int j = 0; j < 5; ++j) lin += v[j] * vw1[j];
    float xa[6];
#pragma unroll
    for (int c = 0; c < 6; ++c) {
        float s = 0.f;
#pragma unroll
        for (int j = 0; j < 5; ++j) s += v[j] * vw2[c * 5 + j];
        xa[c] = s;
    }
    out[b * T_ + t] = lin + xa[0] * xa[3] + xa[1] * xa[4] + xa[2] * xa[5];
}

extern "C" void kernel_launch(void* const* d_in, const int* in_sizes, int n_in,
                              void* d_out, int out_size, void* d_ws, size_t ws_size,
                              hipStream_t stream) {
    const float* x      = (const float*)d_in[0];
    const float* w_in   = (const float*)d_in[1];
    const float* w_res  = (const float*)d_in[2];
    const float* w_skip = (const float*)d_in[3];
    const float* w2     = (const float*)d_in[4];
    const float* w3     = (const float*)d_in[5];
    const float* w4     = (const float*)d_in[6];
    const float* vw1    = (const float*)d_in[7];
    const float* vw2    = (const float*)d_in[8];

    float* ws = (float*)d_ws;
    const size_t HSZ = (size_t)B_ * 64 * T_;     // 16,384,000 elements
    unsigned short* hA   = (unsigned short*)ws;  // fp16 plane
    unsigned short* hB   = hA + HSZ;
    unsigned short* skip = hB + HSZ;             // fp16 plane
    unsigned short* pA   = skip + HSZ;           // post-net fp16 planes
    unsigned short* pB   = pA + HSZ;
    float*    y      = (float*)(pB + HSZ);
    float*    wresT  = y + (size_t)B_ * T_;
    float*    wskipT = wresT + 10 * 3 * 64 * 128;
    float*    w2T    = wskipT + 10 * 3 * 64 * 128;
    float*    w3T    = w2T + 3 * 64 * 64;

    k_tr<<<dim3(960), 256, 0, stream>>>(w_res, wresT, 10, 128, 64);
    k_tr<<<dim3(960), 256, 0, stream>>>(w_skip, wskipT, 10, 128, 64);
    k_tr<<<dim3(48), 256, 0, stream>>>(w2, w2T, 1, 64, 64);
    k_tr<<<dim3(48), 256, 0, stream>>>(w3, w3T, 1, 64, 64);

    k_in<<<dim3(T_ / 256, 64, B_), 256, 0, stream>>>(x, w_in, hA);

    unsigned short *cur = hA, *nxt = hB;
    for (int li = 0; li < 20; ++li) {
        int i = li % 10;
        int d = 1 << i;
        const float* wr = wresT + i * 3 * 64 * 128;
        const float* wk = wskipT + i * 3 * 64 * 128;
        if (li == 0)
            k_layer<0><<<dim3(NSTRIP * B_), 256, 0, stream>>>(cur, nxt, skip, wr, wk, d);
        else
            k_layer<1><<<dim3(NSTRIP * B_), 256, 0, stream>>>(cur, nxt, skip, wr, wk, d);
        unsigned short* t = cur; cur = nxt; nxt = t;
    }

    // post-net: tanh(skip) -> conv w2 (tanh) -> conv w3 (tanh) -> w4 (tanh) -> VNN
    k_post<1><<<dim3(NSTRIP, B_), 256, 0, stream>>>(skip, pB, w2T);
    k_post<0><<<dim3(NSTRIP, B_), 256, 0, stream>>>(pB, pA, w3T);
    k_last<<<dim3(T_ / 256, B_), 256, 0, stream>>>(pA, w4, y);
    k_vnn<<<dim3(T_ / 256, B_), 256, 0, stream>>>(y, vw1, vw2, (float*)d_out);
}

// Round 24
// 1545.107 us; speedup vs baseline: 1.0119x; 1.0008x over previous
//
#include <hip/hip_runtime.h>

#define B_ 8
#define T_ 32000
#define NSTEP 21
#define STRIP 336                   // 21*16; 96 strips x 8 batches = 768 blocks
#define NSTRIP 96                   // = exactly one residency round at 3 blk/CU

typedef __attribute__((ext_vector_type(8))) _Float16 half8;
typedef __attribute__((ext_vector_type(4))) float f32x4;
typedef __attribute__((ext_vector_type(4))) unsigned u32x4;
typedef __attribute__((ext_vector_type(4))) unsigned short u16x4;

#define MFMA(a, b, c) __builtin_amdgcn_mfma_f32_16x16x32_f16(a, b, c, 0, 0, 0)

__device__ __forceinline__ float ftanh(float x) {
    return 1.0f - 2.0f / (1.0f + __expf(2.0f * x));
}
__device__ __forceinline__ unsigned short f2h(float x) {
    _Float16 h = (_Float16)x;
    return __builtin_bit_cast(unsigned short, h);
}
__device__ __forceinline__ float h2f(unsigned short u) {
    return (float)__builtin_bit_cast(_Float16, u);
}
// tanh(x)*sigmoid(y) with 2 exp + 1 rcp
__device__ __forceinline__ float gate(float x, float y) {
    float e2x = __expf(2.0f * x);
    float eny = __expf(-y);
    return (e2x - 1.0f) / ((e2x + 1.0f) * (1.0f + eny));
}

// transpose [L][OC][IC][3] -> [L][3][IC][OC]
__global__ void k_tr(const float* __restrict__ src, float* __restrict__ dst,
                     int L, int OC, int IC) {
    int n = L * OC * IC * 3;
    int idx = blockIdx.x * 256 + threadIdx.x;
    if (idx >= n) return;
    int j = idx % 3;
    int ic = (idx / 3) % IC;
    int oc = (idx / (3 * IC)) % OC;
    int l = idx / (3 * IC * OC);
    dst[((l * 3 + j) * IC + ic) * OC + oc] = src[idx];
}

// h = cconv(x, w_in) -> single fp16 plane
__global__ void k_in(const float* __restrict__ x, const float* __restrict__ w_in,
                     unsigned short* __restrict__ hH) {
    int t = blockIdx.x * 256 + threadIdx.x;
    int c = blockIdx.y, b = blockIdx.z;
    const float* xb = x + b * T_;
    float w0 = w_in[c * 3], w1 = w_in[c * 3 + 1], w2 = w_in[c * 3 + 2];
    float acc = w2 * xb[t];
    if (t >= 1) acc += w1 * xb[t - 1];
    if (t >= 2) acc += w0 * xb[t - 2];
    hH[(size_t)(b * 64 + c) * T_ + t] = f2h(acc);
}

// ---------------- fused residual layer (two-pass over a 336-col strip) --------
// pass A (2-term conv1, DEFERRED gating): step sp's gate+sG-write runs during
//   step sp+1, before its MFMAs (TRANS/MFMA co-issue; gate off the barrier path)
// pass B: o = cconv_1(gated, wskip); hout = hin + o[:64] (fp16); skip += o[64:]
// LDS 48.25 KB -> exactly 3 blocks/CU (hard limit: 4 thrashes L2, R8/R9/R19).
// Grid 768 = one full residency round. Interior blocks skip prefetch guards.
// NOTE: pass-B RMW prefetch tested R22 -> WRITE +20MB, regression; inline loads.
template <int ACC>
__global__ __launch_bounds__(256, 3)
void k_layer(const unsigned short* __restrict__ hinH,
             unsigned short* __restrict__ houtH,
             unsigned short* __restrict__ skip,
             const float* __restrict__ wrT,   // [3][64][128]
             const float* __restrict__ wkT,   // [3][64][128]
             int d) {
    __shared__ __align__(16) unsigned sH[3 * 512];             // fp16 [j][c16][icp32 swz]
    __shared__ __align__(16) unsigned short sG[(STRIP + 2) * 64]; // fp16 [gc][ic swz]

    const int tid = threadIdx.x;
    const int lane = tid & 63;
    const int ocg = tid >> 6;        // 0..3
    const int cc = lane & 15;
    const int kb = lane >> 4;        // 0..3
    const int bb = blockIdx.x & 7;           // XCD-aware: one batch per XCD
    const int tbase = (blockIdx.x >> 3) * STRIP;
    const unsigned short* hbH = hinH + (size_t)bb * 64 * T_;
    // guard-free prefetch path valid when no tap can go below 0 or past T_
    const bool interior = (tbase >= 16 + 2 * d) && (tbase + STRIP <= T_);

    half8 whA[6], wlA[6], whB[6], wlB[6];

    // ---- conv1 weights (fp16 split-2): g-channels cA (tanh), cA+64 (sig) ----
    {
        const int cA = 16 * ocg + cc, cB = cA + 64;
#pragma unroll
        for (int q = 0; q < 6; ++q) {
            const int j = q >> 1, icb = (q & 1) * 32 + kb * 8;
            const float* wp = wrT + (j * 64 + icb) * 128;
#pragma unroll
            for (int jj = 0; jj < 8; ++jj) {
                float wa = wp[jj * 128 + cA];
                _Float16 wh = (_Float16)wa;
                whA[q][jj] = wh;
                wlA[q][jj] = (_Float16)(wa - (float)wh);
                float wb = wp[jj * 128 + cB];
                wh = (_Float16)wb;
                whB[q][jj] = wh;
                wlB[q][jj] = (_Float16)(wb - (float)wh);
            }
        }
    }

    // ---- per-thread staging addresses (constant over steps) ----
    int tof[6];
    unsigned ro[6];
    int wA[6];
#pragma unroll
    for (int it = 0; it < 6; ++it) {
        int idx = it * 256 + tid;          // < 1536
        int j = idx >> 9;
        int r = idx & 511;
        int icp = r >> 4;                  // channel pair 0..31
        int c = r & 15;
        tof[it] = tbase - 16 + c - d * (2 - j);   // t at sp=0 (halo step)
        ro[it] = (unsigned)(2 * icp) * T_;
        wA[it] = j * 512 + c * 32 + (icp ^ ((c & 7) * 4));
    }

    unsigned ra[6], rb[6];
#pragma unroll
    for (int it = 0; it < 6; ++it) {
        int t = tof[it];
        ra[it] = 0u; rb[it] = 0u;
        if (t >= 0 && t < T_) { ra[it] = hbH[ro[it] + t]; rb[it] = hbH[ro[it] + T_ + t]; }
    }

    const int usb = cc * 64;               // ds_read col base (u16 units)
    const int swz = (cc & 7) * 8;
    const int cA = 16 * ocg + cc;

    // ---- pass A: NSTEP+1 steps (sp=0 is the halo step s=-1) ----
    // Deferred gating: step sp's gate+sG write happens at iteration sp+1,
    // placed before that iteration's MFMAs (independent pipes -> co-issue).
    f32x4 pA_ = {0.f, 0.f, 0.f, 0.f}, pB_ = {0.f, 0.f, 0.f, 0.f};
    for (int sp = 0; sp < NSTEP + 1; ++sp) {
        __syncthreads();                   // WAR on sH
#pragma unroll
        for (int it = 0; it < 6; ++it) {
            sH[wA[it]] = ra[it] | (rb[it] << 16);   // (h[2icp], h[2icp+1])
        }
        __syncthreads();                   // sH visible
        // prefetch next step's values (hidden under MFMA burst + gating)
        if (sp < NSTEP) {
            if (interior) {                // wave-uniform: no bounds checks
#pragma unroll
                for (int it = 0; it < 6; ++it) {
                    int t = tof[it] + (sp + 1) * 16;
                    ra[it] = hbH[ro[it] + t];
                    rb[it] = hbH[ro[it] + T_ + t];
                }
            } else {
#pragma unroll
                for (int it = 0; it < 6; ++it) {
                    int t = tof[it] + (sp + 1) * 16;
                    unsigned va = 0u, vb = 0u;
                    if (t >= 0 && t < T_) { va = hbH[ro[it] + t]; vb = hbH[ro[it] + T_ + t]; }
                    ra[it] = va; rb[it] = vb;
                }
            }
        }

        // deferred gate of previous step's accumulators (no MFMA dependency)
        if (sp > 0) {
            const int gcb = (sp - 2) * 16 + kb * 4 + 2;
#pragma unroll
            for (int r = 0; r < 4; ++r) {
                int gc = gcb + r;
                if (sp > 1 || gc >= 0) {
                    float gv = gate(pA_[r], pB_[r]);
                    sG[gc * 64 + (cA ^ ((gc & 7) * 8))] = f2h(gv);
                }
            }
        }

        f32x4 accA = {0.f, 0.f, 0.f, 0.f}, accB = {0.f, 0.f, 0.f, 0.f};
#pragma unroll
        for (int q = 0; q < 6; ++q) {
            const int j = q >> 1;
            const int ic0 = (q & 1) * 32 + kb * 8;
            const int us = j * 1024 + usb + (ic0 ^ swz);
            half8 ah = *(const half8*)((const unsigned short*)sH + us);
            accA = MFMA(ah, whA[q], accA);
            accA = MFMA(ah, wlA[q], accA);
            accB = MFMA(ah, whB[q], accB);
            accB = MFMA(ah, wlB[q], accB);
        }
        pA_ = accA; pB_ = accB;
    }
    // flush final step's gate (sp = NSTEP)
    {
        const int gcb = (NSTEP - 1) * 16 + kb * 4 + 2;
#pragma unroll
        for (int r = 0; r < 4; ++r) {
            int gc = gcb + r;
            float gv = gate(pA_[r], pB_[r]);
            sG[gc * 64 + (cA ^ ((gc & 7) * 8))] = f2h(gv);
        }
    }
    __syncthreads();

    // ---- conv2 weights: waves 0,1 -> residual oc, waves 2,3 -> skip oc ----
    const int oc0 = 32 * ocg + cc;
    const int oc1 = oc0 + 16;
#pragma unroll
    for (int q = 0; q < 6; ++q) {
        const int j = q >> 1, icb = (q & 1) * 32 + kb * 8;
        const float* wp = wkT + (j * 64 + icb) * 128;
#pragma unroll
        for (int jj = 0; jj < 8; ++jj) {
            float wa = wp[jj * 128 + oc0];
            _Float16 wh = (_Float16)wa;
            whA[q][jj] = wh;
            wlA[q][jj] = (_Float16)(wa - (float)wh);
            float wb = wp[jj * 128 + oc1];
            wh = (_Float16)wb;
            whB[q][jj] = wh;
            wlB[q][jj] = (_Float16)(wb - (float)wh);
        }
    }

    // ---- pass B: pure MFMA burst (A-operand exact fp16 -> 2-term) ----
    for (int s = 0; s < NSTEP; ++s) {
        if (tbase + s * 16 >= T_) break;   // partial last strip (80-col tail)
        f32x4 aA = {0.f, 0.f, 0.f, 0.f}, aB = {0.f, 0.f, 0.f, 0.f};
#pragma unroll
        for (int q = 0; q < 6; ++q) {
            const int ic0 = (q & 1) * 32 + kb * 8;
            const int gc = s * 16 + cc + (q >> 1);
            const int us = gc * 64 + (ic0 ^ ((gc & 7) * 8));
            half8 a = *(const half8*)(sG + us);
            aA = MFMA(a, whA[q], aA);
            aA = MFMA(a, wlA[q], aA);
            aB = MFMA(a, whB[q], aB);
            aB = MFMA(a, wlB[q], aB);
        }
        const int trow = tbase + s * 16 + kb * 4;
        if (ocg < 2) {
            // residual channels: fp16 carry
            size_t o0 = ((size_t)bb * 64 + oc0) * T_ + trow;
            u16x4 hiv = *(const u16x4*)(hinH + o0);
            u16x4 oh;
#pragma unroll
            for (int r = 0; r < 4; ++r) oh[r] = f2h(h2f(hiv[r]) + aA[r]);
            *(u16x4*)(houtH + o0) = oh;
            size_t o1 = ((size_t)bb * 64 + oc1) * T_ + trow;
            hiv = *(const u16x4*)(hinH + o1);
#pragma unroll
            for (int r = 0; r < 4; ++r) oh[r] = f2h(h2f(hiv[r]) + aB[r]);
            *(u16x4*)(houtH + o1) = oh;
        } else {
            // skip channels: single fp16 plane RMW
            size_t o0 = ((size_t)bb * 64 + (oc0 - 64)) * T_ + trow;
            u16x4 ov;
            if (ACC) {
                u16x4 sv = *(const u16x4*)(skip + o0);
#pragma unroll
                for (int r = 0; r < 4; ++r) ov[r] = f2h(h2f(sv[r]) + aA[r]);
            } else {
#pragma unroll
                for (int r = 0; r < 4; ++r) ov[r] = f2h(aA[r]);
            }
            *(u16x4*)(skip + o0) = ov;
            size_t o1 = ((size_t)bb * 64 + (oc1 - 64)) * T_ + trow;
            if (ACC) {
                u16x4 sv = *(const u16x4*)(skip + o1);
#pragma unroll
                for (int r = 0; r < 4; ++r) ov[r] = f2h(h2f(sv[r]) + aB[r]);
            } else {
#pragma unroll
                for (int r = 0; r < 4; ++r) ov[r] = f2h(aB[r]);
            }
            *(u16x4*)(skip + o1) = ov;
        }
    }
}

// ---------------- post-net 64->64 conv (k=3,d=1), fp16 in/out -----------------
// INTANH=1: apply tanh on input read (skip buffer).
template <int INTANH>
__global__ __launch_bounds__(256)
void k_post(const unsigned short* __restrict__ in_, unsigned short* __restrict__ out,
            const float* __restrict__ wT /* [3][64][64] */) {
    __shared__ __align__(16) unsigned sHi[(18 * 64) / 2];
    __shared__ __align__(16) unsigned sLo[(18 * 64) / 2];
    const int tid = threadIdx.x;
    const int lane = tid & 63;
    const int ocg = tid >> 6;
    const int cc = lane & 15;
    const int kb = lane >> 4;
    const int bb = blockIdx.y;
    const int tbase = blockIdx.x * STRIP;
    const unsigned short* ib = in_ + (size_t)bb * 64 * T_;

    const int oc = 16 * ocg + cc;
    half8 wh[6], wl[6];
#pragma unroll
    for (int q = 0; q < 6; ++q) {
        const int j = q >> 1, icb = (q & 1) * 32 + kb * 8;
        const float* wp = wT + (j * 64 + icb) * 64;
#pragma unroll
        for (int jj = 0; jj < 8; ++jj) {
            float wv = wp[jj * 64 + oc];
            _Float16 h = (_Float16)wv;
            wh[q][jj] = h;
            wl[q][jj] = (_Float16)(wv - (float)h);
        }
    }

    for (int step = 0; step < NSTEP; ++step) {
        const int t0 = tbase + step * 16;
        if (t0 >= T_) break;               // partial last strip
#pragma unroll
        for (int it = 0; it < 3; ++it) {
            int idx = it * 256 + tid;
            if (idx < 576) {
                int ic2 = idx / 18;
                int c = idx - ic2 * 18;
                int t = t0 - 2 + c;
                float v0 = 0.f, v1 = 0.f;
                if (t >= 0 && t < T_) {
                    v0 = h2f(ib[(size_t)(2 * ic2) * T_ + t]);
                    v1 = h2f(ib[(size_t)(2 * ic2 + 1) * T_ + t]);
                    if (INTANH) { v0 = ftanh(v0); v1 = ftanh(v1); }
                }
                unsigned short h0 = f2h(v0), h1 = f2h(v1);
                unsigned short l0 = f2h(v0 - h2f(h0)), l1 = f2h(v1 - h2f(h1));
                int w = c * 32 + (ic2 ^ ((c & 7) * 4));
                sHi[w] = (unsigned)h0 | ((unsigned)h1 << 16);
                sLo[w] = (unsigned)l0 | ((unsigned)l1 << 16);
            }
        }
        __syncthreads();

        f32x4 acc = {0.f, 0.f, 0.f, 0.f};
#pragma unroll
        for (int q = 0; q < 6; ++q) {
            const int j = q >> 1;
            const int ic0 = (q & 1) * 32 + kb * 8;
            const int c = cc + j;
            const int us = c * 64 + (ic0 ^ ((c & 7) * 8));
            half8 ah = *(const half8*)((const unsigned short*)sHi + us);
            half8 al = *(const half8*)((const unsigned short*)sLo + us);
            acc = MFMA(ah, wh[q], acc);
            acc = MFMA(al, wh[q], acc);
            acc = MFMA(ah, wl[q], acc);
        }
        __syncthreads();

        const int trow = t0 + kb * 4;
        u16x4 o;
#pragma unroll
        for (int r = 0; r < 4; ++r) o[r] = f2h(ftanh(acc[r]));
        *(u16x4*)(out + ((size_t)bb * 64 + oc) * T_ + trow) = o;
    }
}

// y = tanh(cconv(in, w4)), 64 -> 1 channel (fp16 input plane)
__global__ void k_last(const unsigned short* __restrict__ in,
                       const float* __restrict__ w4, float* __restrict__ y) {
    int t = blockIdx.x * 256 + threadIdx.x;
    int b = blockIdx.y;
    const unsigned short* ib = in + (size_t)b * 64 * T_;
    float acc = 0.f;
    for (int ic = 0; ic < 64; ++ic) {
        const unsigned short* r = ib + (size_t)ic * T_;
        float s = w4[ic * 3 + 2] * h2f(r[t]);
        if (t >= 1) s += w4[ic * 3 + 1] * h2f(r[t - 1]);
        if (t >= 2) s += w4[ic * 3 + 0] * h2f(r[t - 2]);
        acc += s;
    }
    y[b * T_ + t] = ftanh(acc);
}

// VNN2
__global__ void k_vnn(const float* __restrict__ y, const float* __restrict__ vw1,
                      const float* __restrict__ vw2, float* __restrict__ out) {
    int t = blockIdx.x * 256 + threadIdx.x;
    int b = blockIdx.y;
    const float* yb = y + b * T_;
    float v[5];
#pragma unroll
    for (int j = 0; j < 5; ++j) {
        int tt = t - 4 + j;
        v[j] = (tt >= 0) ? yb[tt] : 0.f;
    }
    float lin = 0.f;
#pragma unroll
    for (int j = 0; j < 5; ++j) lin += v[j] * vw1[j];
    float xa[6];
#pragma unroll
    for (int c = 0; c < 6; ++c) {
        float s = 0.f;
#pragma unroll
        for (int j = 0; j < 5; ++j) s += v[j] * vw2[c * 5 + j];
        xa[c] = s;
    }
    out[b * T_ + t] = lin + xa[0] * xa[3] + xa[1] * xa[4] + xa[2] * xa[5];
}

extern "C" void kernel_launch(void* const* d_in, const int* in_sizes, int n_in,
                              void* d_out, int out_size, void* d_ws, size_t ws_size,
                              hipStream_t stream) {
    const float* x      = (const float*)d_in[0];
    const float* w_in   = (const float*)d_in[1];
    const float* w_res  = (const float*)d_in[2];
    const float* w_skip = (const float*)d_in[3];
    const float* w2     = (const float*)d_in[4];
    const float* w3     = (const float*)d_in[5];
    const float* w4     = (const float*)d_in[6];
    const float* vw1    = (const float*)d_in[7];
    const float* vw2    = (const float*)d_in[8];

    float* ws = (float*)d_ws;
    const size_t HSZ = (size_t)B_ * 64 * T_;     // 16,384,000 elements
    unsigned short* hA   = (unsigned short*)ws;  // fp16 plane
    unsigned short* hB   = hA + HSZ;
    unsigned short* skip = hB + HSZ;             // fp16 plane
    unsigned short* pA   = skip + HSZ;           // post-net fp16 planes
    unsigned short* pB   = pA + HSZ;
    float*    y      = (float*)(pB + HSZ);
    float*    wresT  = y + (size_t)B_ * T_;
    float*    wskipT = wresT + 10 * 3 * 64 * 128;
    float*    w2T    = wskipT + 10 * 3 * 64 * 128;
    float*    w3T    = w2T + 3 * 64 * 64;

    k_tr<<<dim3(960), 256, 0, stream>>>(w_res, wresT, 10, 128, 64);
    k_tr<<<dim3(960), 256, 0, stream>>>(w_skip, wskipT, 10, 128, 64);
    k_tr<<<dim3(48), 256, 0, stream>>>(w2, w2T, 1, 64, 64);
    k_tr<<<dim3(48), 256, 0, stream>>>(w3, w3T, 1, 64, 64);

    k_in<<<dim3(T_ / 256, 64, B_), 256, 0, stream>>>(x, w_in, hA);

    unsigned short *cur = hA, *nxt = hB;
    for (int li = 0; li < 20; ++li) {
        int i = li % 10;
        int d = 1 << i;
        const float* wr = wresT + i * 3 * 64 * 128;
        const float* wk = wskipT + i * 3 * 64 * 128;
        if (li == 0)
            k_layer<0><<<dim3(NSTRIP * B_), 256, 0, stream>>>(cur, nxt, skip, wr, wk, d);
        else
            k_layer<1><<<dim3(NSTRIP * B_), 256, 0, stream>>>(cur, nxt, skip, wr, wk, d);
        unsigned short* t = cur; cur = nxt; nxt = t;
    }

    // post-net: tanh(skip) -> conv w2 (tanh) -> conv w3 (tanh) -> w4 (tanh) -> VNN
    k_post<1><<<dim3(NSTRIP, B_), 256, 0, stream>>>(skip, pB, w2T);
    k_post<0><<<dim3(NSTRIP, B_), 256, 0, stream>>>(pB, pA, w3T);
    k_last<<<dim3(T_ / 256, B_), 256, 0, stream>>>(pA, w4, y);
    k_vnn<<<dim3(T_ / 256, B_), 256, 0, stream>>>(y, vw1, vw2, (float*)d_out);
}

// Round 25
// 1507.911 us; speedup vs baseline: 1.0368x; 1.0247x over previous
//
#include <hip/hip_runtime.h>

#define B_ 8
#define T_ 32000
#define NSTEP 21
#define STRIP 336                   // 21*16; 96 strips x 8 batches = 768 blocks
#define NSTRIP 96                   // = exactly one residency round at 3 blk/CU

typedef __attribute__((ext_vector_type(8))) _Float16 half8;
typedef __attribute__((ext_vector_type(4))) float f32x4;
typedef __attribute__((ext_vector_type(4))) unsigned u32x4;
typedef __attribute__((ext_vector_type(4))) unsigned short u16x4;

#define MFMA(a, b, c) __builtin_amdgcn_mfma_f32_16x16x32_f16(a, b, c, 0, 0, 0)

__device__ __forceinline__ float ftanh(float x) {
    return 1.0f - 2.0f / (1.0f + __expf(2.0f * x));
}
__device__ __forceinline__ unsigned short f2h(float x) {
    _Float16 h = (_Float16)x;
    return __builtin_bit_cast(unsigned short, h);
}
__device__ __forceinline__ float h2f(unsigned short u) {
    return (float)__builtin_bit_cast(_Float16, u);
}
// tanh(x)*sigmoid(y) with 2 exp + 1 rcp
__device__ __forceinline__ float gate(float x, float y) {
    float e2x = __expf(2.0f * x);
    float eny = __expf(-y);
    return (e2x - 1.0f) / ((e2x + 1.0f) * (1.0f + eny));
}

// transpose [L][OC][IC][3] -> [L][3][IC][OC]
__global__ void k_tr(const float* __restrict__ src, float* __restrict__ dst,
                     int L, int OC, int IC) {
    int n = L * OC * IC * 3;
    int idx = blockIdx.x * 256 + threadIdx.x;
    if (idx >= n) return;
    int j = idx % 3;
    int ic = (idx / 3) % IC;
    int oc = (idx / (3 * IC)) % OC;
    int l = idx / (3 * IC * OC);
    dst[((l * 3 + j) * IC + ic) * OC + oc] = src[idx];
}

// h = cconv(x, w_in) -> single fp16 plane
__global__ void k_in(const float* __restrict__ x, const float* __restrict__ w_in,
                     unsigned short* __restrict__ hH) {
    int t = blockIdx.x * 256 + threadIdx.x;
    int c = blockIdx.y, b = blockIdx.z;
    const float* xb = x + b * T_;
    float w0 = w_in[c * 3], w1 = w_in[c * 3 + 1], w2 = w_in[c * 3 + 2];
    float acc = w2 * xb[t];
    if (t >= 1) acc += w1 * xb[t - 1];
    if (t >= 2) acc += w0 * xb[t - 2];
    hH[(size_t)(b * 64 + c) * T_ + t] = f2h(acc);
}

// ---------------- fused residual layer (two-pass over a 336-col strip) --------
// pass A (2-term conv1, deferred gating): g = cconv_d(h_fp16, wres split-2)
//   ALIGNED=1 (even d) interior blocks: staging via u32 loads (2 t-cols per
//   VMEM instr) -> pass-A VMEM issue count halves. Same bytes, same sH layout.
// pass B: o = cconv_1(gated, wskip); hout = hin + o[:64] (fp16); skip += o[64:]
// LDS 48.25 KB -> exactly 3 blocks/CU (hard limit: 4 thrashes L2, R8/R9/R19).
// Grid 768 = one full residency round.
template <int ACC, int ALIGNED>
__global__ __launch_bounds__(256, 3)
void k_layer(const unsigned short* __restrict__ hinH,
             unsigned short* __restrict__ houtH,
             unsigned short* __restrict__ skip,
             const float* __restrict__ wrT,   // [3][64][128]
             const float* __restrict__ wkT,   // [3][64][128]
             int d) {
    __shared__ __align__(16) unsigned sH[3 * 512];             // fp16 [j][c16][icp32 swz]
    __shared__ __align__(16) unsigned short sG[(STRIP + 2) * 64]; // fp16 [gc][ic swz]

    const int tid = threadIdx.x;
    const int lane = tid & 63;
    const int ocg = tid >> 6;        // 0..3
    const int cc = lane & 15;
    const int kb = lane >> 4;        // 0..3
    const int bb = blockIdx.x & 7;           // XCD-aware: one batch per XCD
    const int tbase = (blockIdx.x >> 3) * STRIP;
    const unsigned short* hbH = hinH + (size_t)bb * 64 * T_;
    const bool interior = (tbase >= 16 + 2 * d) && (tbase + STRIP <= T_);

    half8 whA[6], wlA[6], whB[6], wlB[6];

    // ---- conv1 weights (fp16 split-2): g-channels cA (tanh), cA+64 (sig) ----
    {
        const int cA = 16 * ocg + cc, cB = cA + 64;
#pragma unroll
        for (int q = 0; q < 6; ++q) {
            const int j = q >> 1, icb = (q & 1) * 32 + kb * 8;
            const float* wp = wrT + (j * 64 + icb) * 128;
#pragma unroll
            for (int jj = 0; jj < 8; ++jj) {
                float wa = wp[jj * 128 + cA];
                _Float16 wh = (_Float16)wa;
                whA[q][jj] = wh;
                wlA[q][jj] = (_Float16)(wa - (float)wh);
                float wb = wp[jj * 128 + cB];
                wh = (_Float16)wb;
                whB[q][jj] = wh;
                wlB[q][jj] = (_Float16)(wb - (float)wh);
            }
        }
    }

    const int usb = cc * 64;               // ds_read col base (u16 units)
    const int swz = (cc & 7) * 8;
    const int cA = 16 * ocg + cc;

    f32x4 pA_ = {0.f, 0.f, 0.f, 0.f}, pB_ = {0.f, 0.f, 0.f, 0.f};

    if (ALIGNED && interior) {
        // ---- vectorized staging: 768 u32-pair slots = (j:3, icp:32, c2:8) ----
        int t00[3];
        unsigned ro2[3];
        int w0[3], w1[3];
#pragma unroll
        for (int it = 0; it < 3; ++it) {
            int idx = it * 256 + tid;      // < 768
            int c2 = idx & 7;
            int icp = (idx >> 3) & 31;
            int j = idx >> 8;
            int c0 = 2 * c2;
            t00[it] = tbase - 16 + c0 - d * (2 - j);   // even (d even)
            ro2[it] = (unsigned)(2 * icp) * T_;
            w0[it] = j * 512 + c0 * 32 + (icp ^ ((c0 & 7) * 4));
            w1[it] = j * 512 + (c0 + 1) * 32 + (icp ^ (((c0 + 1) & 7) * 4));
        }
        unsigned la[3], lb[3];
#pragma unroll
        for (int it = 0; it < 3; ++it) {
            la[it] = *(const unsigned*)(hbH + ro2[it] + t00[it]);
            lb[it] = *(const unsigned*)(hbH + ro2[it] + T_ + t00[it]);
        }

        for (int sp = 0; sp < NSTEP + 1; ++sp) {
            __syncthreads();               // WAR on sH
#pragma unroll
            for (int it = 0; it < 3; ++it) {
                sH[w0[it]] = (la[it] & 0xffffu) | (lb[it] << 16);
                sH[w1[it]] = (la[it] >> 16) | (lb[it] & 0xffff0000u);
            }
            __syncthreads();               // sH visible
            if (sp < NSTEP) {
#pragma unroll
                for (int it = 0; it < 3; ++it) {
                    la[it] = *(const unsigned*)(hbH + ro2[it] + t00[it] + (sp + 1) * 16);
                    lb[it] = *(const unsigned*)(hbH + ro2[it] + T_ + t00[it] + (sp + 1) * 16);
                }
            }

            // deferred gate of previous step's accumulators
            if (sp > 0) {
                const int gcb = (sp - 2) * 16 + kb * 4 + 2;
#pragma unroll
                for (int r = 0; r < 4; ++r) {
                    int gc = gcb + r;
                    if (sp > 1 || gc >= 0) {
                        float gv = gate(pA_[r], pB_[r]);
                        sG[gc * 64 + (cA ^ ((gc & 7) * 8))] = f2h(gv);
                    }
                }
            }

            f32x4 accA = {0.f, 0.f, 0.f, 0.f}, accB = {0.f, 0.f, 0.f, 0.f};
#pragma unroll
            for (int q = 0; q < 6; ++q) {
                const int j = q >> 1;
                const int ic0 = (q & 1) * 32 + kb * 8;
                const int us = j * 1024 + usb + (ic0 ^ swz);
                half8 ah = *(const half8*)((const unsigned short*)sH + us);
                accA = MFMA(ah, whA[q], accA);
                accA = MFMA(ah, wlA[q], accA);
                accB = MFMA(ah, whB[q], accB);
                accB = MFMA(ah, wlB[q], accB);
            }
            pA_ = accA; pB_ = accB;
        }
    } else {
        // ---- scalar staging path (boundary blocks / odd d) ----
        int tof[6];
        unsigned ro[6];
        int wA[6];
#pragma unroll
        for (int it = 0; it < 6; ++it) {
            int idx = it * 256 + tid;      // < 1536
            int j = idx >> 9;
            int r = idx & 511;
            int icp = r >> 4;
            int c = r & 15;
            tof[it] = tbase - 16 + c - d * (2 - j);
            ro[it] = (unsigned)(2 * icp) * T_;
            wA[it] = j * 512 + c * 32 + (icp ^ ((c & 7) * 4));
        }
        unsigned ra[6], rb[6];
#pragma unroll
        for (int it = 0; it < 6; ++it) {
            int t = tof[it];
            ra[it] = 0u; rb[it] = 0u;
            if (t >= 0 && t < T_) { ra[it] = hbH[ro[it] + t]; rb[it] = hbH[ro[it] + T_ + t]; }
        }

        for (int sp = 0; sp < NSTEP + 1; ++sp) {
            __syncthreads();               // WAR on sH
#pragma unroll
            for (int it = 0; it < 6; ++it) {
                sH[wA[it]] = ra[it] | (rb[it] << 16);
            }
            __syncthreads();               // sH visible
            if (sp < NSTEP) {
#pragma unroll
                for (int it = 0; it < 6; ++it) {
                    int t = tof[it] + (sp + 1) * 16;
                    unsigned va = 0u, vb = 0u;
                    if (t >= 0 && t < T_) { va = hbH[ro[it] + t]; vb = hbH[ro[it] + T_ + t]; }
                    ra[it] = va; rb[it] = vb;
                }
            }

            if (sp > 0) {
                const int gcb = (sp - 2) * 16 + kb * 4 + 2;
#pragma unroll
                for (int r = 0; r < 4; ++r) {
                    int gc = gcb + r;
                    if (sp > 1 || gc >= 0) {
                        float gv = gate(pA_[r], pB_[r]);
                        sG[gc * 64 + (cA ^ ((gc & 7) * 8))] = f2h(gv);
                    }
                }
            }

            f32x4 accA = {0.f, 0.f, 0.f, 0.f}, accB = {0.f, 0.f, 0.f, 0.f};
#pragma unroll
            for (int q = 0; q < 6; ++q) {
                const int j = q >> 1;
                const int ic0 = (q & 1) * 32 + kb * 8;
                const int us = j * 1024 + usb + (ic0 ^ swz);
                half8 ah = *(const half8*)((const unsigned short*)sH + us);
                accA = MFMA(ah, whA[q], accA);
                accA = MFMA(ah, wlA[q], accA);
                accB = MFMA(ah, whB[q], accB);
                accB = MFMA(ah, wlB[q], accB);
            }
            pA_ = accA; pB_ = accB;
        }
    }
    // flush final step's gate (sp = NSTEP)
    {
        const int gcb = (NSTEP - 1) * 16 + kb * 4 + 2;
#pragma unroll
        for (int r = 0; r < 4; ++r) {
            int gc = gcb + r;
            float gv = gate(pA_[r], pB_[r]);
            sG[gc * 64 + (cA ^ ((gc & 7) * 8))] = f2h(gv);
        }
    }
    __syncthreads();

    // ---- conv2 weights: waves 0,1 -> residual oc, waves 2,3 -> skip oc ----
    const int oc0 = 32 * ocg + cc;
    const int oc1 = oc0 + 16;
#pragma unroll
    for (int q = 0; q < 6; ++q) {
        const int j = q >> 1, icb = (q & 1) * 32 + kb * 8;
        const float* wp = wkT + (j * 64 + icb) * 128;
#pragma unroll
        for (int jj = 0; jj < 8; ++jj) {
            float wa = wp[jj * 128 + oc0];
            _Float16 wh = (_Float16)wa;
            whA[q][jj] = wh;
            wlA[q][jj] = (_Float16)(wa - (float)wh);
            float wb = wp[jj * 128 + oc1];
            wh = (_Float16)wb;
            whB[q][jj] = wh;
            wlB[q][jj] = (_Float16)(wb - (float)wh);
        }
    }

    // ---- pass B: pure MFMA burst (A-operand exact fp16 -> 2-term) ----
    for (int s = 0; s < NSTEP; ++s) {
        if (tbase + s * 16 >= T_) break;   // partial last strip (80-col tail)
        f32x4 aA = {0.f, 0.f, 0.f, 0.f}, aB = {0.f, 0.f, 0.f, 0.f};
#pragma unroll
        for (int q = 0; q < 6; ++q) {
            const int ic0 = (q & 1) * 32 + kb * 8;
            const int gc = s * 16 + cc + (q >> 1);
            const int us = gc * 64 + (ic0 ^ ((gc & 7) * 8));
            half8 a = *(const half8*)(sG + us);
            aA = MFMA(a, whA[q], aA);
            aA = MFMA(a, wlA[q], aA);
            aB = MFMA(a, whB[q], aB);
            aB = MFMA(a, wlB[q], aB);
        }
        const int trow = tbase + s * 16 + kb * 4;
        if (ocg < 2) {
            // residual channels: fp16 carry
            size_t o0 = ((size_t)bb * 64 + oc0) * T_ + trow;
            u16x4 hiv = *(const u16x4*)(hinH + o0);
            u16x4 oh;
#pragma unroll
            for (int r = 0; r < 4; ++r) oh[r] = f2h(h2f(hiv[r]) + aA[r]);
            *(u16x4*)(houtH + o0) = oh;
            size_t o1 = ((size_t)bb * 64 + oc1) * T_ + trow;
            hiv = *(const u16x4*)(hinH + o1);
#pragma unroll
            for (int r = 0; r < 4; ++r) oh[r] = f2h(h2f(hiv[r]) + aB[r]);
            *(u16x4*)(houtH + o1) = oh;
        } else {
            // skip channels: single fp16 plane RMW
            size_t o0 = ((size_t)bb * 64 + (oc0 - 64)) * T_ + trow;
            u16x4 ov;
            if (ACC) {
                u16x4 sv = *(const u16x4*)(skip + o0);
#pragma unroll
                for (int r = 0; r < 4; ++r) ov[r] = f2h(h2f(sv[r]) + aA[r]);
            } else {
#pragma unroll
                for (int r = 0; r < 4; ++r) ov[r] = f2h(aA[r]);
            }
            *(u16x4*)(skip + o0) = ov;
            size_t o1 = ((size_t)bb * 64 + (oc1 - 64)) * T_ + trow;
            if (ACC) {
                u16x4 sv = *(const u16x4*)(skip + o1);
#pragma unroll
                for (int r = 0; r < 4; ++r) ov[r] = f2h(h2f(sv[r]) + aB[r]);
            } else {
#pragma unroll
                for (int r = 0; r < 4; ++r) ov[r] = f2h(aB[r]);
            }
            *(u16x4*)(skip + o1) = ov;
        }
    }
}

// ---------------- post-net 64->64 conv (k=3,d=1), fp16 in/out -----------------
// INTANH=1: apply tanh on input read (skip buffer).
template <int INTANH>
__global__ __launch_bounds__(256)
void k_post(const unsigned short* __restrict__ in_, unsigned short* __restrict__ out,
            const float* __restrict__ wT /* [3][64][64] */) {
    __shared__ __align__(16) unsigned sHi[(18 * 64) / 2];
    __shared__ __align__(16) unsigned sLo[(18 * 64) / 2];
    const int tid = threadIdx.x;
    const int lane = tid & 63;
    const int ocg = tid >> 6;
    const int cc = lane & 15;
    const int kb = lane >> 4;
    const int bb = blockIdx.y;
    const int tbase = blockIdx.x * STRIP;
    const unsigned short* ib = in_ + (size_t)bb * 64 * T_;

    const int oc = 16 * ocg + cc;
    half8 wh[6], wl[6];
#pragma unroll
    for (int q = 0; q < 6; ++q) {
        const int j = q >> 1, icb = (q & 1) * 32 + kb * 8;
        const float* wp = wT + (j * 64 + icb) * 64;
#pragma unroll
        for (int jj = 0; jj < 8; ++jj) {
            float wv = wp[jj * 64 + oc];
            _Float16 h = (_Float16)wv;
            wh[q][jj] = h;
            wl[q][jj] = (_Float16)(wv - (float)h);
        }
    }

    for (int step = 0; step < NSTEP; ++step) {
        const int t0 = tbase + step * 16;
        if (t0 >= T_) break;               // partial last strip
#pragma unroll
        for (int it = 0; it < 3; ++it) {
            int idx = it * 256 + tid;
            if (idx < 576) {
                int ic2 = idx / 18;
                int c = idx - ic2 * 18;
                int t = t0 - 2 + c;
                float v0 = 0.f, v1 = 0.f;
                if (t >= 0 && t < T_) {
                    v0 = h2f(ib[(size_t)(2 * ic2) * T_ + t]);
                    v1 = h2f(ib[(size_t)(2 * ic2 + 1) * T_ + t]);
                    if (INTANH) { v0 = ftanh(v0); v1 = ftanh(v1); }
                }
                unsigned short h0 = f2h(v0), h1 = f2h(v1);
                unsigned short l0 = f2h(v0 - h2f(h0)), l1 = f2h(v1 - h2f(h1));
                int w = c * 32 + (ic2 ^ ((c & 7) * 4));
                sHi[w] = (unsigned)h0 | ((unsigned)h1 << 16);
                sLo[w] = (unsigned)l0 | ((unsigned)l1 << 16);
            }
        }
        __syncthreads();

        f32x4 acc = {0.f, 0.f, 0.f, 0.f};
#pragma unroll
        for (int q = 0; q < 6; ++q) {
            const int j = q >> 1;
            const int ic0 = (q & 1) * 32 + kb * 8;
            const int c = cc + j;
            const int us = c * 64 + (ic0 ^ ((c & 7) * 8));
            half8 ah = *(const half8*)((const unsigned short*)sHi + us);
            half8 al = *(const half8*)((const unsigned short*)sLo + us);
            acc = MFMA(ah, wh[q], acc);
            acc = MFMA(al, wh[q], acc);
            acc = MFMA(ah, wl[q], acc);
        }
        __syncthreads();

        const int trow = t0 + kb * 4;
        u16x4 o;
#pragma unroll
        for (int r = 0; r < 4; ++r) o[r] = f2h(ftanh(acc[r]));
        *(u16x4*)(out + ((size_t)bb * 64 + oc) * T_ + trow) = o;
    }
}

// y = tanh(cconv(in, w4)), 64 -> 1 channel (fp16 input plane)
__global__ void k_last(const unsigned short* __restrict__ in,
                       const float* __restrict__ w4, float* __restrict__ y) {
    int t = blockIdx.x * 256 + threadIdx.x;
    int b = blockIdx.y;
    const unsigned short* ib = in + (size_t)b * 64 * T_;
    float acc = 0.f;
    for (int ic = 0; ic < 64; ++ic) {
        const unsigned short* r = ib + (size_t)ic * T_;
        float s = w4[ic * 3 + 2] * h2f(r[t]);
        if (t >= 1) s += w4[ic * 3 + 1] * h2f(r[t - 1]);
        if (t >= 2) s += w4[ic * 3 + 0] * h2f(r[t - 2]);
        acc += s;
    }
    y[b * T_ + t] = ftanh(acc);
}

// VNN2
__global__ void k_vnn(const float* __restrict__ y, const float* __restrict__ vw1,
                      const float* __restrict__ vw2, float* __restrict__ out) {
    int t = blockIdx.x * 256 + threadIdx.x;
    int b = blockIdx.y;
    const float* yb = y + b * T_;
    float v[5];
#pragma unroll
    for (int j = 0; j < 5; ++j) {
        int tt = t - 4 + j;
        v[j] = (tt >= 0) ? yb[tt] : 0.f;
    }
    float lin = 0.f;
#pragma unroll
    for (int j = 0; j < 5; ++j) lin += v[j] * vw1[j];
    float xa[6];
#pragma unroll
    for (int c = 0; c < 6; ++c) {
        float s = 0.f;
#pragma unroll
        for (int j = 0; j < 5; ++j) s += v[j] * vw2[c * 5 + j];
        xa[c] = s;
    }
    out[b * T_ + t] = lin + xa[0] * xa[3] + xa[1] * xa[4] + xa[2] * xa[5];
}

extern "C" void kernel_launch(void* const* d_in, const int* in_sizes, int n_in,
                              void* d_out, int out_size, void* d_ws, size_t ws_size,
                              hipStream_t stream) {
    const float* x      = (const float*)d_in[0];
    const float* w_in   = (const float*)d_in[1];
    const float* w_res  = (const float*)d_in[2];
    const float* w_skip = (const float*)d_in[3];
    const float* w2     = (const float*)d_in[4];
    const float* w3     = (const float*)d_in[5];
    const float* w4     = (const float*)d_in[6];
    const float* vw1    = (const float*)d_in[7];
    const float* vw2    = (const float*)d_in[8];

    float* ws = (float*)d_ws;
    const size_t HSZ = (size_t)B_ * 64 * T_;     // 16,384,000 elements
    unsigned short* hA   = (unsigned short*)ws;  // fp16 plane
    unsigned short* hB   = hA + HSZ;
    unsigned short* skip = hB + HSZ;             // fp16 plane
    unsigned short* pA   = skip + HSZ;           // post-net fp16 planes
    unsigned short* pB   = pA + HSZ;
    float*    y      = (float*)(pB + HSZ);
    float*    wresT  = y + (size_t)B_ * T_;
    float*    wskipT = wresT + 10 * 3 * 64 * 128;
    float*    w2T    = wskipT + 10 * 3 * 64 * 128;
    float*    w3T    = w2T + 3 * 64 * 64;

    k_tr<<<dim3(960), 256, 0, stream>>>(w_res, wresT, 10, 128, 64);
    k_tr<<<dim3(960), 256, 0, stream>>>(w_skip, wskipT, 10, 128, 64);
    k_tr<<<dim3(48), 256, 0, stream>>>(w2, w2T, 1, 64, 64);
    k_tr<<<dim3(48), 256, 0, stream>>>(w3, w3T, 1, 64, 64);

    k_in<<<dim3(T_ / 256, 64, B_), 256, 0, stream>>>(x, w_in, hA);

    unsigned short *cur = hA, *nxt = hB;
    for (int li = 0; li < 20; ++li) {
        int i = li % 10;
        int d = 1 << i;
        const float* wr = wresT + i * 3 * 64 * 128;
        const float* wk = wskipT + i * 3 * 64 * 128;
        if (li == 0)
            k_layer<0, 0><<<dim3(NSTRIP * B_), 256, 0, stream>>>(cur, nxt, skip, wr, wk, d);
        else if (d == 1)
            k_layer<1, 0><<<dim3(NSTRIP * B_), 256, 0, stream>>>(cur, nxt, skip, wr, wk, d);
        else
            k_layer<1, 1><<<dim3(NSTRIP * B_), 256, 0, stream>>>(cur, nxt, skip, wr, wk, d);
        unsigned short* t = cur; cur = nxt; nxt = t;
    }

    // post-net: tanh(skip) -> conv w2 (tanh) -> conv w3 (tanh) -> w4 (tanh) -> VNN
    k_post<1><<<dim3(NSTRIP, B_), 256, 0, stream>>>(skip, pB, w2T);
    k_post<0><<<dim3(NSTRIP, B_), 256, 0, stream>>>(pB, pA, w3T);
    k_last<<<dim3(T_ / 256, B_), 256, 0, stream>>>(pA, w4, y);
    k_vnn<<<dim3(T_ / 256, B_), 256, 0, stream>>>(y, vw1, vw2, (float*)d_out);
}